// Round 7
// baseline (600.511 us; speedup 1.0000x reference)
//
#include <hip/hip_runtime.h>
#include <hip/hip_cooperative_groups.h>

namespace cg = cooperative_groups;

#define N_NODES 200000
#define N_EDGES 600000
#define F_IN 165
#define F_HID 128
#define KP 200    // row stride (ushorts) for wt/Bs/As
#define NT 6250   // 200000/32 row-tiles
#define G1 512    // K1 grid (2 blocks/CU, LDS-limited -> co-resident)
#define GT1 (G1 * 256)
#define G2 1024   // K2 grid (4 blocks/CU guaranteed by launch_bounds)

typedef short short8 __attribute__((ext_vector_type(8)));
typedef float f32x4 __attribute__((ext_vector_type(4)));

__device__ __forceinline__ unsigned short f2bf(float f) {
  union { float f; unsigned int u; } v; v.f = f;
  unsigned int u = v.u;
  return (unsigned short)((u + 0x7FFFu + ((u >> 16) & 1u)) >> 16);  // RNE
}
__device__ __forceinline__ float bflo(unsigned int v) {
  union { unsigned int u; float f; } x; x.u = v << 16; return x.f;
}
__device__ __forceinline__ float bfhi(unsigned int v) {
  union { unsigned int u; float f; } x; x.u = v & 0xffff0000u; return x.f;
}

// ============ K1: CSR build + GEMM1, one cooperative kernel ============
__global__ __launch_bounds__(256) void k_fused1(const float* __restrict__ x,
                                                const int* __restrict__ ei,
                                                const float* __restrict__ W1,
                                                int* __restrict__ cnt,
                                                int* __restrict__ bsum,
                                                int* __restrict__ rowptr,
                                                int* __restrict__ fill,
                                                int* __restrict__ srcl,
                                                float* __restrict__ dinv,
                                                unsigned short* __restrict__ wt,
                                                unsigned short* __restrict__ h16) {
  cg::grid_group grid = cg::this_grid();
  __shared__ unsigned short Bs[F_HID * KP];  // 51200 B (W^T, staged once)
  __shared__ unsigned short As[32 * KP];     // 12800 B (x tile; scan scratch early)
  int tid = threadIdx.x, bid = blockIdx.x;
  int g = bid * 256 + tid;

  // ---- P0: zero cnt; build wt = W1^T bf16 padded [128][KP] ----
  for (int i = g; i < N_NODES; i += GT1) cnt[i] = 0;
  for (int i = g; i < F_HID * KP; i += GT1) {
    int c = i / KP, k = i - c * KP;
    wt[i] = (k < F_IN) ? f2bf(W1[k * F_HID + c]) : (unsigned short)0;
  }
  grid.sync();

  // ---- P1: count in-degrees; then stage Bs (overlaps other blocks' atomics) ----
  for (int e = g; e < N_EDGES; e += GT1) atomicAdd(&cnt[ei[N_EDGES + e]], 1);
  {
    const uint4* wt4 = (const uint4*)wt;
    uint4* Bs4 = (uint4*)Bs;
    for (int j = tid; j < F_HID * KP / 8; j += 256) Bs4[j] = wt4[j];
  }
  grid.sync();

  // ---- P2a: chunked scan; thread owns cnt[2g], cnt[2g+1] (block covers 512 contiguous) ----
  int i0 = 2 * g;
  int c0 = (i0 < N_NODES) ? cnt[i0] : 0;
  int c1 = (i0 + 1 < N_NODES) ? cnt[i0 + 1] : 0;
  int mysum = c0 + c1;
  int* sd = (int*)As;
  sd[tid] = mysum;
  __syncthreads();
  #pragma unroll
  for (int off = 1; off < 256; off <<= 1) {
    int u = (tid >= off) ? sd[tid - off] : 0;
    __syncthreads();
    sd[tid] += u;
    __syncthreads();
  }
  int myoff = sd[tid] - mysum;  // exclusive within block (register, survives grid.sync)
  if (tid == 255) bsum[bid] = sd[tid];
  grid.sync();

  // ---- P2b: block 0 exclusive-scans bsum[G1] (2 entries/thread) ----
  if (bid == 0) {
    int a = bsum[2 * tid], b = bsum[2 * tid + 1];
    int ps = a + b;
    __syncthreads();
    sd[tid] = ps;
    __syncthreads();
    #pragma unroll
    for (int off = 1; off < 256; off <<= 1) {
      int u = (tid >= off) ? sd[tid - off] : 0;
      __syncthreads();
      sd[tid] += u;
      __syncthreads();
    }
    int ex = sd[tid] - ps;
    bsum[2 * tid] = ex;
    bsum[2 * tid + 1] = ex + a;
  }
  grid.sync();

  // ---- P2c: rowptr / fill cursor / dinv ----
  int base = bsum[bid] + myoff;
  if (i0 < N_NODES) {
    rowptr[i0] = base; fill[i0] = base;
    dinv[i0] = rsqrtf((float)(c0 + 1));
  }
  if (i0 + 1 < N_NODES) {
    int b2 = base + c0;
    rowptr[i0 + 1] = b2; fill[i0 + 1] = b2;
    dinv[i0 + 1] = rsqrtf((float)(c1 + 1));
  }
  if (g == 0) rowptr[N_NODES] = N_EDGES;
  grid.sync();

  // ---- P3: fill srcl (atomic slots). No grid.sync after: gemm below touches
  //      disjoint buffers (wt/dinv/x -> h16); K2's launch boundary orders srcl. ----
  for (int e = g; e < N_EDGES; e += GT1) {
    int d = ei[N_EDGES + e];
    int s = ei[e];
    srcl[atomicAdd(&fill[d], 1)] = s;
  }

  // ---- P4: GEMM1 (round-4 structure: persistent, As double-phase, reg prefetch) ----
  // zero As pad region (k in [165,200)); per-tile staging writes only k<165
  for (int j = tid; j < 32 * (KP - F_IN); j += 256) {
    int r = j / (KP - F_IN), c = F_IN + (j - (j / (KP - F_IN)) * (KP - F_IN));
    As[r * KP + c] = 0;
  }
  int t = bid;
  {  // prologue: stage first tile
    const float4* x4 = (const float4*)(x + (long)t * 32 * F_IN);  // 21120B chunks, 16B-aligned
    for (int j = tid; j < 32 * F_IN / 4; j += 256) {
      float4 v = x4[j];
      int e = 4 * j;
      #pragma unroll
      for (int u = 0; u < 4; ++u) {
        int ee = e + u;
        int r = ee / F_IN, c = ee - r * F_IN;
        As[r * KP + c] = f2bf((&v.x)[u]);
      }
    }
  }
  __syncthreads();

  int lane = tid & 63;
  int w = tid >> 6;
  int rg = w & 1;   // row group (16 rows)
  int ch = w >> 1;  // col half (64 cols)
  int arow = rg * 16 + (lane & 15);
  int kg = (lane >> 4) * 8;

  while (t < NT) {
    int tn = t + G1;
    bool have = tn < NT;  // uniform across block

    // phase 1: issue next tile's global loads into registers
    float4 vals[6];
    if (have) {
      const float4* x4 = (const float4*)(x + (long)tn * 32 * F_IN);
      #pragma unroll
      for (int i = 0; i < 6; ++i) {
        int j = tid + i * 256;
        if (j < 32 * F_IN / 4) vals[i] = x4[j];
      }
    }

    // phase 2: compute current tile
    f32x4 acc[4];
    #pragma unroll
    for (int i = 0; i < 4; ++i) acc[i] = (f32x4){0.f, 0.f, 0.f, 0.f};
    #pragma unroll
    for (int ks = 0; ks < 6; ++ks) {
      short8 af = *(const short8*)(&As[arow * KP + ks * 32 + kg]);
      #pragma unroll
      for (int cb = 0; cb < 4; ++cb) {
        int col = (ch * 4 + cb) * 16 + (lane & 15);
        short8 bf = *(const short8*)(&Bs[col * KP + ks * 32 + kg]);
        acc[cb] = __builtin_amdgcn_mfma_f32_16x16x32_bf16(af, bf, acc[cb], 0, 0, 0);
      }
    }
    // C/D layout: col = lane&15, row = (lane>>4)*4 + reg; scale by dinv, store bf16
    long orow = (long)t * 32 + rg * 16 + (lane >> 4) * 4;
    int ocol = lane & 15;
    float dv[4];
    #pragma unroll
    for (int j = 0; j < 4; ++j) dv[j] = dinv[orow + j];
    #pragma unroll
    for (int cb = 0; cb < 4; ++cb) {
      #pragma unroll
      for (int j = 0; j < 4; ++j) {
        h16[(orow + j) * F_HID + (ch * 4 + cb) * 16 + ocol] = f2bf(acc[cb][j] * dv[j]);
      }
    }
    __syncthreads();  // all reads of As done

    // phase 3: convert + write prefetched tile into As
    if (have) {
      #pragma unroll
      for (int i = 0; i < 6; ++i) {
        int j = tid + i * 256;
        if (j < 32 * F_IN / 4) {
          int e = 4 * j;
          #pragma unroll
          for (int u = 0; u < 4; ++u) {
            int ee = e + u;
            int r = ee / F_IN, c = ee - r * F_IN;
            As[r * KP + c] = f2bf((&vals[i].x)[u]);
          }
        }
      }
    }
    __syncthreads();
    t = tn;
  }
}

// ============ K2: agg1 (gather+bias+relu+W2) -> grid.sync -> agg2 ============
__global__ __launch_bounds__(256, 4) void k_fused2(const unsigned int* __restrict__ H,
                                                   const float* __restrict__ dinv,
                                                   const int* __restrict__ rowptr,
                                                   const int* __restrict__ srcl,
                                                   const float* __restrict__ b1,
                                                   const float* __restrict__ W2,
                                                   const float* __restrict__ b2,
                                                   float* __restrict__ h2s,
                                                   float* __restrict__ out) {
  cg::grid_group grid = cg::this_grid();
  int tid = threadIdx.x;
  int local = tid >> 6;
  int lane = tid & 63;

  // ---- agg1: 4 nodes/block, 64 lanes/node, 4-wide gather unroll ----
  for (int d4 = blockIdx.x; d4 < N_NODES / 4; d4 += G2) {
    int d = d4 * 4 + local;
    unsigned int v = H[(long)d * 64 + lane];  // self (already dinv[d]-scaled)
    float acc0 = bflo(v), acc1 = bfhi(v);
    int r0 = rowptr[d], r1 = rowptr[d + 1];
    int n = r1 - r0;
    for (int b = 0; b < n; b += 4) {
      int i0 = r0 + b;
      bool m1 = b + 1 < n, m2 = b + 2 < n, m3 = b + 3 < n;
      int s0 = srcl[i0];
      int s1 = m1 ? srcl[i0 + 1] : s0;
      int s2 = m2 ? srcl[i0 + 2] : s0;
      int s3 = m3 ? srcl[i0 + 3] : s0;
      unsigned int v0 = H[(long)s0 * 64 + lane];
      unsigned int v1 = H[(long)s1 * 64 + lane];
      unsigned int v2 = H[(long)s2 * 64 + lane];
      unsigned int v3 = H[(long)s3 * 64 + lane];
      acc0 += bflo(v0);                            acc1 += bfhi(v0);
      acc0 = fmaf(m1 ? 1.f : 0.f, bflo(v1), acc0); acc1 = fmaf(m1 ? 1.f : 0.f, bfhi(v1), acc1);
      acc0 = fmaf(m2 ? 1.f : 0.f, bflo(v2), acc0); acc1 = fmaf(m2 ? 1.f : 0.f, bfhi(v2), acc1);
      acc0 = fmaf(m3 ? 1.f : 0.f, bflo(v3), acc0); acc1 = fmaf(m3 ? 1.f : 0.f, bfhi(v3), acc1);
    }
    float dd = dinv[d];
    float2 bb = ((const float2*)b1)[lane];
    float a0 = fmaxf(fmaf(acc0, dd, bb.x), 0.f);
    float a1 = fmaxf(fmaf(acc1, dd, bb.y), 0.f);
    float4 w2 = ((const float4*)W2)[lane];
    float p0 = a0 * w2.x + a1 * w2.z;
    float p1 = a0 * w2.y + a1 * w2.w;
    #pragma unroll
    for (int off = 32; off > 0; off >>= 1) {
      p0 += __shfl_down(p0, off);
      p1 += __shfl_down(p1, off);
    }
    if (lane == 0) ((float2*)h2s)[d] = make_float2(p0 * dd, p1 * dd);
  }
  grid.sync();

  // ---- agg2: 2-feature aggregation + bias ----
  const float2* Gv = (const float2*)h2s;
  for (int d = blockIdx.x * 256 + tid; d < N_NODES; d += G2 * 256) {
    float2 gv = Gv[d];
    float o0 = gv.x, o1 = gv.y;
    int r0 = rowptr[d], r1 = rowptr[d + 1];
    int n = r1 - r0;
    for (int b = 0; b < n; b += 4) {
      int i0 = r0 + b;
      bool m1 = b + 1 < n, m2 = b + 2 < n, m3 = b + 3 < n;
      int s0 = srcl[i0];
      int s1 = m1 ? srcl[i0 + 1] : s0;
      int s2 = m2 ? srcl[i0 + 2] : s0;
      int s3 = m3 ? srcl[i0 + 3] : s0;
      float2 g0 = Gv[s0], g1 = Gv[s1], g2 = Gv[s2], g3 = Gv[s3];
      o0 += g0.x;                          o1 += g0.y;
      o0 = fmaf(m1 ? 1.f : 0.f, g1.x, o0); o1 = fmaf(m1 ? 1.f : 0.f, g1.y, o1);
      o0 = fmaf(m2 ? 1.f : 0.f, g2.x, o0); o1 = fmaf(m2 ? 1.f : 0.f, g2.y, o1);
      o0 = fmaf(m3 ? 1.f : 0.f, g3.x, o0); o1 = fmaf(m3 ? 1.f : 0.f, g3.y, o1);
    }
    float dd = dinv[d];
    ((float2*)out)[d] = make_float2(fmaf(o0, dd, b2[0]), fmaf(o1, dd, b2[1]));
  }
}

extern "C" void kernel_launch(void* const* d_in, const int* in_sizes, int n_in,
                              void* d_out, int out_size, void* d_ws, size_t ws_size,
                              hipStream_t stream) {
  const float* x  = (const float*)d_in[0];
  const int*   ei = (const int*)d_in[1];
  const float* W1 = (const float*)d_in[2];
  const float* b1 = (const float*)d_in[3];
  const float* W2 = (const float*)d_in[4];
  const float* b2 = (const float*)d_in[5];
  float* out = (float*)d_out;

  char* p = (char*)d_ws;
  size_t off = 0;
  auto take = [&](size_t bytes) -> void* {
    void* r = p + off;
    off += (bytes + 255) & ~(size_t)255;
    return r;
  };
  unsigned short* h16    = (unsigned short*)take((size_t)N_NODES * F_HID * 2);  // 51.2 MB
  unsigned short* wt     = (unsigned short*)take((size_t)F_HID * KP * 2);
  float*          h2s    = (float*)take((size_t)N_NODES * 2 * 4);
  int*            cnt    = (int*)take((size_t)N_NODES * 4);
  int*            fill   = (int*)take((size_t)N_NODES * 4);
  int*            rowptr = (int*)take(((size_t)N_NODES + 1) * 4);
  int*            srcl   = (int*)take(((size_t)N_EDGES + 8) * 4);  // +8 pad for speculative unroll
  float*          dinv   = (float*)take((size_t)N_NODES * 4);
  int*            bsum   = (int*)take((size_t)G1 * 4);
  (void)ws_size; (void)in_sizes; (void)n_in; (void)out_size;

  const unsigned int* H = (const unsigned int*)h16;

  void* a1[] = {(void*)&x, (void*)&ei, (void*)&W1, (void*)&cnt, (void*)&bsum,
                (void*)&rowptr, (void*)&fill, (void*)&srcl, (void*)&dinv,
                (void*)&wt, (void*)&h16};
  hipLaunchCooperativeKernel((const void*)k_fused1, dim3(G1), dim3(256), a1, 0, stream);

  void* a2[] = {(void*)&H, (void*)&dinv, (void*)&rowptr, (void*)&srcl,
                (void*)&b1, (void*)&W2, (void*)&b2, (void*)&h2s, (void*)&out};
  hipLaunchCooperativeKernel((const void*)k_fused2, dim3(G2), dim3(256), a2, 0, stream);
}

// Round 8
// 188.873 us; speedup vs baseline: 3.1794x; 3.1794x over previous
//
#include <hip/hip_runtime.h>

#define N_NODES 200000
#define N_EDGES 600000
#define F_IN 165
#define F_HID 128
#define KP 200    // row stride (ushorts) for wt/As
#define NT 6250   // 200000/32 row-tiles

typedef short short8 __attribute__((ext_vector_type(8)));
typedef float f32x4 __attribute__((ext_vector_type(4)));

__device__ __forceinline__ unsigned short f2bf(float f) {
  union { float f; unsigned int u; } v; v.f = f;
  unsigned int u = v.u;
  return (unsigned short)((u + 0x7FFFu + ((u >> 16) & 1u)) >> 16);  // RNE
}
__device__ __forceinline__ float bflo(unsigned int v) {
  union { unsigned int u; float f; } x; x.u = v << 16; return x.f;
}
__device__ __forceinline__ float bfhi(unsigned int v) {
  union { unsigned int u; float f; } x; x.u = v & 0xffff0000u; return x.f;
}

// ---- zero scratch counters + build W1^T bf16 [128][KP] (graph-replayed) ----
__global__ void k_zero(int* __restrict__ cnt, const float* __restrict__ W1,
                       unsigned short* __restrict__ wt) {
  int i = blockIdx.x * 256 + threadIdx.x;
  if (i < N_NODES) cnt[i] = 0;
  if (i < F_HID * KP) {
    int c = i / KP, k = i - c * KP;
    wt[i] = (k < F_IN) ? f2bf(W1[k * F_HID + c]) : (unsigned short)0;
  }
}

// ---- CSR build ----
__global__ void k_count(const int* __restrict__ ei, int* __restrict__ cnt) {
  int e = blockIdx.x * 256 + threadIdx.x;
  if (e < N_EDGES) atomicAdd(&cnt[ei[N_EDGES + e]], 1);
}

__global__ void k_scan1(const int* __restrict__ cnt, int* __restrict__ rowptr, int* __restrict__ bsum) {
  __shared__ int sd[256];
  int t = threadIdx.x;
  int idx = blockIdx.x * 256 + t;
  int v = (idx < N_NODES) ? cnt[idx] : 0;
  sd[t] = v; __syncthreads();
  #pragma unroll
  for (int off = 1; off < 256; off <<= 1) {
    int u = (t >= off) ? sd[t - off] : 0;
    __syncthreads();
    sd[t] += u;
    __syncthreads();
  }
  if (idx < N_NODES) rowptr[idx] = sd[t] - v;  // exclusive within block
  if (t == 255) bsum[blockIdx.x] = sd[t];
}

__global__ void k_scan2(int* __restrict__ bsum, int nb) {
  __shared__ int sd[1024];
  int t = threadIdx.x;
  int v = (t < nb) ? bsum[t] : 0;
  sd[t] = v; __syncthreads();
  for (int off = 1; off < 1024; off <<= 1) {
    int u = (t >= off) ? sd[t - off] : 0;
    __syncthreads();
    sd[t] += u;
    __syncthreads();
  }
  if (t < nb) bsum[t] = sd[t] - v;  // exclusive block offsets
}

__global__ void k_scan3(const int* __restrict__ cnt, const int* __restrict__ bsum,
                        int* __restrict__ rowptr, int* __restrict__ fill, float* __restrict__ dinv) {
  int idx = blockIdx.x * 256 + threadIdx.x;
  if (idx < N_NODES) {
    int rp = rowptr[idx] + bsum[blockIdx.x];
    rowptr[idx] = rp;
    fill[idx] = rp;  // mutable cursor for k_fill
    dinv[idx] = rsqrtf((float)(cnt[idx] + 1));  // deg = in-degree + self-loop >= 1
  }
  if (idx == 0) rowptr[N_NODES] = N_EDGES;
}

__global__ void k_fill(const int* __restrict__ ei, int* __restrict__ fill, int* __restrict__ srcl) {
  int e = blockIdx.x * 256 + threadIdx.x;
  if (e < N_EDGES) {
    int d = ei[N_EDGES + e];
    int s = ei[e];
    int slot = atomicAdd(&fill[d], 1);
    srcl[slot] = s;
  }
}

// ---- GEMM1: persistent, 4 blocks/CU. Wave w owns col-quarter (32 cols); W-quarter
//      in 48 VGPRs; LDS = 12.8KB A-tile only; 2 barriers/tile; swapped-operand MFMA
//      (epilogue layout verified in round 5: lane owns x-row, regs give 4 consecutive cols). ----
__global__ __launch_bounds__(256, 4) void k_gemm1(const float* __restrict__ x,
                                                  const unsigned short* __restrict__ wt,
                                                  const float* __restrict__ dinv,
                                                  unsigned short* __restrict__ h16) {
  __shared__ unsigned short As[32 * KP];  // 12800 B
  int tid = threadIdx.x;
  int lane = tid & 63;
  int w = tid >> 6;        // col-quarter
  int lane15 = lane & 15;
  int kq = (lane >> 4) * 8;

  // hoist W-quarter: 2 col-blocks x 6 k-steps = 48 VGPRs
  short8 wf[2][6];
  {
    int c0 = w * 32 + lane15;
    #pragma unroll
    for (int cb = 0; cb < 2; ++cb) {
      #pragma unroll
      for (int ks = 0; ks < 6; ++ks) {
        wf[cb][ks] = *(const short8*)(&wt[(c0 + cb * 16) * KP + ks * 32 + kq]);
      }
    }
  }

  // zero As pad region (k in [165,200)) once; staging writes only k<165
  for (int j = tid; j < 32 * (KP - F_IN); j += 256) {
    int r = j / (KP - F_IN), c = F_IN + (j - (j / (KP - F_IN)) * (KP - F_IN));
    As[r * KP + c] = 0;
  }

  for (int t = blockIdx.x; t < NT; t += gridDim.x) {
    __syncthreads();  // previous tile's As reads done (no-op first iter)

    // stage A-tile: 32 rows fp32 -> bf16
    const float4* x4 = (const float4*)(x + (long)t * 32 * F_IN);  // 21120B chunks, 16B-aligned
    for (int j = tid; j < 32 * F_IN / 4; j += 256) {
      float4 v = x4[j];
      int e = 4 * j;
      #pragma unroll
      for (int u = 0; u < 4; ++u) {
        int ee = e + u;
        int r = ee / F_IN, c = ee - r * F_IN;
        As[r * KP + c] = f2bf((&v.x)[u]);
      }
    }
    __syncthreads();

    // compute: 2 row-groups x 2 col-blocks x 6 k-steps = 24 MFMA, 12 ds_read_b128
    f32x4 acc[2][2];
    #pragma unroll
    for (int rg = 0; rg < 2; ++rg)
      #pragma unroll
      for (int cb = 0; cb < 2; ++cb) acc[rg][cb] = (f32x4){0.f, 0.f, 0.f, 0.f};
    #pragma unroll
    for (int rg = 0; rg < 2; ++rg) {
      int arow = rg * 16 + lane15;
      #pragma unroll
      for (int ks = 0; ks < 6; ++ks) {
        short8 xf = *(const short8*)(&As[arow * KP + ks * 32 + kq]);
        acc[rg][0] = __builtin_amdgcn_mfma_f32_16x16x32_bf16(wf[0][ks], xf, acc[rg][0], 0, 0, 0);
        acc[rg][1] = __builtin_amdgcn_mfma_f32_16x16x32_bf16(wf[1][ks], xf, acc[rg][1], 0, 0, 0);
      }
    }

    // epilogue: lane owns row rg*16+lane15; scale by dinv, pack 4 bf16 -> 8B stores
    #pragma unroll
    for (int rg = 0; rg < 2; ++rg) {
      long row = (long)t * 32 + rg * 16 + lane15;
      float dd = dinv[row];
      unsigned short* hp = &h16[row * F_HID + w * 32 + (lane >> 4) * 4];
      #pragma unroll
      for (int cb = 0; cb < 2; ++cb) {
        unsigned int p0 = (unsigned int)f2bf(acc[rg][cb][0] * dd) | ((unsigned int)f2bf(acc[rg][cb][1] * dd) << 16);
        unsigned int p1 = (unsigned int)f2bf(acc[rg][cb][2] * dd) | ((unsigned int)f2bf(acc[rg][cb][3] * dd) << 16);
        uint2 pp; pp.x = p0; pp.y = p1;
        *(uint2*)(hp + cb * 16) = pp;
      }
    }
  }
}

// ---- fused: agg1 (gather, 4-wide) + bias + relu + GEMM2 (128->2) ; output pre-scaled by dinv ----
__global__ __launch_bounds__(256) void k_agg1(const unsigned int* __restrict__ H,  // bf16x2 rows, 64 uints/node
                                              const float* __restrict__ dinv,
                                              const int* __restrict__ rowptr, const int* __restrict__ srcl,
                                              const float* __restrict__ b1, const float* __restrict__ W2,
                                              float* __restrict__ h2s) {
  int tid = threadIdx.x;
  int local = tid >> 6;
  int lane = tid & 63;
  int d = blockIdx.x * 4 + local;  // grid exact: 50000*4 = 200000

  unsigned int v = H[(long)d * 64 + lane];  // self (already dinv[d]-scaled)
  float acc0 = bflo(v), acc1 = bfhi(v);
  int r0 = rowptr[d], r1 = rowptr[d + 1];
  int n = r1 - r0;
  for (int b = 0; b < n; b += 4) {
    int i0 = r0 + b;
    bool m1 = b + 1 < n, m2 = b + 2 < n, m3 = b + 3 < n;
    int s0 = srcl[i0];
    int s1 = m1 ? srcl[i0 + 1] : s0;
    int s2 = m2 ? srcl[i0 + 2] : s0;
    int s3 = m3 ? srcl[i0 + 3] : s0;
    unsigned int v0 = H[(long)s0 * 64 + lane];
    unsigned int v1 = H[(long)s1 * 64 + lane];
    unsigned int v2 = H[(long)s2 * 64 + lane];
    unsigned int v3 = H[(long)s3 * 64 + lane];
    acc0 += bflo(v0);                            acc1 += bfhi(v0);
    acc0 = fmaf(m1 ? 1.f : 0.f, bflo(v1), acc0); acc1 = fmaf(m1 ? 1.f : 0.f, bfhi(v1), acc1);
    acc0 = fmaf(m2 ? 1.f : 0.f, bflo(v2), acc0); acc1 = fmaf(m2 ? 1.f : 0.f, bfhi(v2), acc1);
    acc0 = fmaf(m3 ? 1.f : 0.f, bflo(v3), acc0); acc1 = fmaf(m3 ? 1.f : 0.f, bfhi(v3), acc1);
  }
  float dd = dinv[d];
  float2 bb = ((const float2*)b1)[lane];
  float a0 = fmaxf(fmaf(acc0, dd, bb.x), 0.f);
  float a1 = fmaxf(fmaf(acc1, dd, bb.y), 0.f);
  float4 w2 = ((const float4*)W2)[lane];  // W2[2*lane][0..1], W2[2*lane+1][0..1]
  float p0 = a0 * w2.x + a1 * w2.z;
  float p1 = a0 * w2.y + a1 * w2.w;
  #pragma unroll
  for (int off = 32; off > 0; off >>= 1) {
    p0 += __shfl_down(p0, off);
    p1 += __shfl_down(p1, off);
  }
  if (lane == 0) ((float2*)h2s)[d] = make_float2(p0 * dd, p1 * dd);
}

// ---- agg2 over 2 features + bias (h2s pre-scaled by dinv) ----
__global__ void k_agg2(const float* __restrict__ h2s, const float* __restrict__ dinv,
                       const int* __restrict__ rowptr, const int* __restrict__ srcl,
                       const float* __restrict__ b2, float* __restrict__ out) {
  int d = blockIdx.x * 256 + threadIdx.x;
  if (d >= N_NODES) return;
  const float2* G = (const float2*)h2s;
  float2 g = G[d];
  float o0 = g.x, o1 = g.y;
  int r0 = rowptr[d], r1 = rowptr[d + 1];
  int n = r1 - r0;
  for (int b = 0; b < n; b += 4) {
    int i0 = r0 + b;
    bool m1 = b + 1 < n, m2 = b + 2 < n, m3 = b + 3 < n;
    int s0 = srcl[i0];
    int s1 = m1 ? srcl[i0 + 1] : s0;
    int s2 = m2 ? srcl[i0 + 2] : s0;
    int s3 = m3 ? srcl[i0 + 3] : s0;
    float2 g0 = G[s0], g1 = G[s1], g2 = G[s2], g3 = G[s3];
    o0 += g0.x;                          o1 += g0.y;
    o0 = fmaf(m1 ? 1.f : 0.f, g1.x, o0); o1 = fmaf(m1 ? 1.f : 0.f, g1.y, o1);
    o0 = fmaf(m2 ? 1.f : 0.f, g2.x, o0); o1 = fmaf(m2 ? 1.f : 0.f, g2.y, o1);
    o0 = fmaf(m3 ? 1.f : 0.f, g3.x, o0); o1 = fmaf(m3 ? 1.f : 0.f, g3.y, o1);
  }
  float dd = dinv[d];
  ((float2*)out)[d] = make_float2(fmaf(o0, dd, b2[0]), fmaf(o1, dd, b2[1]));
}

extern "C" void kernel_launch(void* const* d_in, const int* in_sizes, int n_in,
                              void* d_out, int out_size, void* d_ws, size_t ws_size,
                              hipStream_t stream) {
  const float* x  = (const float*)d_in[0];
  const int*   ei = (const int*)d_in[1];
  const float* W1 = (const float*)d_in[2];
  const float* b1 = (const float*)d_in[3];
  const float* W2 = (const float*)d_in[4];
  const float* b2 = (const float*)d_in[5];
  float* out = (float*)d_out;

  char* p = (char*)d_ws;
  size_t off = 0;
  auto take = [&](size_t bytes) -> void* {
    void* r = p + off;
    off += (bytes + 255) & ~(size_t)255;
    return r;
  };
  unsigned short* h16    = (unsigned short*)take((size_t)N_NODES * F_HID * 2);  // 51.2 MB, dinv-scaled bf16
  unsigned short* wt     = (unsigned short*)take((size_t)F_HID * KP * 2);
  float*          h2s    = (float*)take((size_t)N_NODES * 2 * 4);
  int*            cnt    = (int*)take((size_t)N_NODES * 4);
  int*            fill   = (int*)take((size_t)N_NODES * 4);
  int*            rowptr = (int*)take(((size_t)N_NODES + 1) * 4);
  int*            srcl   = (int*)take(((size_t)N_EDGES + 8) * 4);  // +8 pad for speculative unroll reads
  float*          dinv   = (float*)take((size_t)N_NODES * 4);
  int*            bsum   = (int*)take(4096);
  (void)ws_size; (void)in_sizes; (void)n_in; (void)out_size;

  int nbE = (N_EDGES + 255) / 256;
  int nbN = (N_NODES + 255) / 256;
  k_zero<<<nbN, 256, 0, stream>>>(cnt, W1, wt);
  k_count<<<nbE, 256, 0, stream>>>(ei, cnt);
  k_scan1<<<nbN, 256, 0, stream>>>(cnt, rowptr, bsum);
  k_scan2<<<1, 1024, 0, stream>>>(bsum, nbN);
  k_scan3<<<nbN, 256, 0, stream>>>(cnt, bsum, rowptr, fill, dinv);
  k_fill<<<nbE, 256, 0, stream>>>(ei, fill, srcl);
  k_gemm1<<<1024, 256, 0, stream>>>(x, wt, dinv, h16);  // persistent, 4 blocks/CU
  k_agg1<<<N_NODES / 4, 256, 0, stream>>>((const unsigned int*)h16, dinv, rowptr, srcl, b1, W2, h2s);
  k_agg2<<<nbN, 256, 0, stream>>>(h2s, dinv, rowptr, srcl, b2, out);
}